// Round 21
// baseline (109.016 us; speedup 1.0000x reference)
//
#include <hip/hip_runtime.h>

typedef float f32x4 __attribute__((ext_vector_type(4)));
typedef short s16x8 __attribute__((ext_vector_type(8)));
typedef unsigned int u32x2 __attribute__((ext_vector_type(2)));
typedef __bf16 bf16x2 __attribute__((ext_vector_type(2)));
typedef unsigned short u16;
typedef unsigned int u32;

#define LOG2E    1.4426950408889634f
#define QK_SCALE_L2E 0.25504614517377436f  // 32^-0.5 * LOG2E

__device__ __forceinline__ u16 f2bf(float f) {
    __bf16 b = (__bf16)f;
    return __builtin_bit_cast(u16, b);
}
__device__ __forceinline__ u32 pk2(float lo, float hi) {
    bf16x2 v;
    v[0] = (__bf16)lo;
    v[1] = (__bf16)hi;
    return __builtin_bit_cast(u32, v);
}
__device__ __forceinline__ float swap32(float v, bool lt32) {
    u32 xi = __builtin_bit_cast(u32, v);
    u32x2 r = __builtin_amdgcn_permlane32_swap(xi, xi, false, false);
    return __builtin_bit_cast(float, lt32 ? r[1] : r[0]);
}
__device__ __forceinline__ float swap16(float v, bool lo16) {
    u32 xi = __builtin_bit_cast(u32, v);
    u32x2 r = __builtin_amdgcn_permlane16_swap(xi, xi, false, false);
    return __builtin_bit_cast(float, lo16 ? r[1] : r[0]);
}

// ---- workspace byte offsets (tables identical to R20) ----
#define WS_PROJW 393216
#define WS_BMC   524288
#define WS_F32_NEED (524288 + 8388608)

__global__ void prep(const float* __restrict__ qkv_w, const float* __restrict__ proj_w,
                     const float* __restrict__ bias_table, const int* __restrict__ rel_index,
                     const float* __restrict__ mask,
                     u16* __restrict__ wqkvC2, u16* __restrict__ projwC,
                     u16* __restrict__ bmC2, float* __restrict__ bmF, int use_f32) {
    int i = blockIdx.x * 256 + threadIdx.x;
    if (i < 196608) {                       // qkv weights: A-frags for W·X^T (Q,K); B-frags for X·Wv^T (V)
        int e = i & 7, lane = (i >> 3) & 63, ks = (i >> 9) & 7, dt = (i >> 12) & 1;
        int i2 = i >> 13, t = i2 % 3, h = i2 / 3;
        int c = lane & 15, g = lane >> 4;
        wqkvC2[i] = f2bf(qkv_w[(t * 256 + h * 32 + dt * 16 + c) * 256 + ks * 32 + g * 8 + e]);
    }
    if (i < 65536) {                        // proj weights -> fragment order
        int e = i & 7, lane = (i >> 3) & 63, ks = (i >> 9) & 7, nt = (i >> 12) & 15;
        int c = lane & 15, g = lane >> 4;
        projwC[i] = f2bf(proj_w[(nt * 16 + c) * 256 + ks * 32 + g * 8 + e]);
    }
    {                                       // merged bias+mask (x LOG2E), St C-frag order
        int j = i & 3, lane = (i >> 2) & 63, mtK = (i >> 8) & 3, ntQ = (i >> 10) & 3;
        int h = (i >> 12) & 7, wi = i >> 15;
        int c = lane & 15, g = lane >> 4;
        int q = ntQ * 16 + c, k = mtK * 16 + g * 4 + j;
        float v;
        if (k < 49) v = (q < 49) ? bias_table[rel_index[q * 49 + k] * 8 + h]
                                   + mask[wi * 2401 + q * 49 + k]
                                 : 0.f;
        else        v = -1e30f;
        v *= LOG2E;
        if (use_f32) bmF[i] = v;
        else         bmC2[i] = f2bf(v);
    }
}

// ---- LDS (u16 offsets), total 38152 u16 = 76,304 B -> 2 blocks/CU ----
// XS  : [0, 12936)  49 rows x 264 (x window, bf16); OUTS overlaps XS after barrier
// per-wave WB = 12936 + wv*6304:
//   Q  : WB,        [tok<50][40]  (2000)
//   K  : WB+2000,   [tok<50][40]  (2000)
//   P  : WB (overlaps Q+K after Qf/Kf regs), [q<50][72] (3600 <= 4000)
//   VT : WB+4000,   [ch32][72]    (2304)
template<bool F32BM>
__global__ __launch_bounds__(256, 2)
void swin_attn(const float* __restrict__ x,
               const float* __restrict__ qkv_b,
               const float* __restrict__ proj_b,
               const u16* __restrict__ wqkvC2,
               const u16* __restrict__ projwC,
               const u16* __restrict__ bmC2,
               const float* __restrict__ bmF,
               float* __restrict__ out) {
    __shared__ __align__(16) u16 sm[38152];
    const int b = blockIdx.x, tid = threadIdx.x;
    const int wv = tid >> 6, lane = tid & 63, g = lane >> 4, c = lane & 15;
    const int wi = b & 63;
    const int WB = 12936 + wv * 6304;
    const float* xw = x + (size_t)b * 12544;

    // stage x window (bf16), rows 0..48
    for (int i = tid; i < 49 * 64; i += 256) {
        int row = i >> 6, q4 = i & 63;
        float4 v = ((const float4*)xw)[i];
        u32x2 s;
        s[0] = pk2(v.x, v.y);
        s[1] = pk2(v.z, v.w);
        *(u32x2*)&sm[row * 264 + q4 * 4] = s;
    }
    __syncthreads();

    const bool lo = lane < 32;
    const bool l16 = (lane & 16) == 0;
    const s16x8 zfrag = {0, 0, 0, 0, 0, 0, 0, 0};

    u32 opk[2][4][2][2];

#pragma unroll
    for (int hl = 0; hl < 2; ++hl) {
        const int h = wv * 2 + hl;

        // ---- QKV: Q,K as W·X^T; V as X·Wv^T (same tables, swapped operands) ----
        f32x4 acc[6][4];
#pragma unroll
        for (int f = 0; f < 6; ++f)
#pragma unroll
            for (int tt = 0; tt < 4; ++tt) acc[f][tt] = f32x4{0.f, 0.f, 0.f, 0.f};

        s16x8 wf[2][6];
#pragma unroll
        for (int f = 0; f < 6; ++f)
            wf[0][f] = *(const s16x8*)&wqkvC2[(((h * 6 + f) * 8 + 0) * 64 + lane) * 8];
        s16x8 Xf[2][4];
#pragma unroll
        for (int tt = 0; tt < 4; ++tt)
            Xf[0][tt] = *(const s16x8*)&sm[(tt * 16 + c) * 264 + g * 8];
        if (c > 0) Xf[0][3] = zfrag;
#pragma unroll
        for (int ks = 0; ks < 8; ++ks) {
            if (ks < 7) {
#pragma unroll
                for (int f = 0; f < 6; ++f)
                    wf[(ks + 1) & 1][f] =
                        *(const s16x8*)&wqkvC2[(((h * 6 + f) * 8 + (ks + 1)) * 64 + lane) * 8];
#pragma unroll
                for (int tt = 0; tt < 4; ++tt)
                    Xf[(ks + 1) & 1][tt] = *(const s16x8*)&sm[(tt * 16 + c) * 264 + (ks + 1) * 32 + g * 8];
                if (c > 0) Xf[(ks + 1) & 1][3] = zfrag;
            }
            __builtin_amdgcn_s_setprio(1);
#pragma unroll
            for (int f = 0; f < 6; ++f)
#pragma unroll
                for (int tt = 0; tt < 4; ++tt) {
                    if (f < 4)
                        acc[f][tt] = __builtin_amdgcn_mfma_f32_16x16x32_bf16(wf[ks & 1][f], Xf[ks & 1][tt], acc[f][tt], 0, 0, 0);
                    else
                        acc[f][tt] = __builtin_amdgcn_mfma_f32_16x16x32_bf16(Xf[ks & 1][tt], wf[ks & 1][f], acc[f][tt], 0, 0, 0);
                }
            __builtin_amdgcn_s_setprio(0);
        }

        // ---- distribute: Q/K -> [tok][ch] packed b64; V -> VT[ch][tok] packed b64 ----
#pragma unroll
        for (int f = 0; f < 6; ++f) {
            int t = f >> 1, dt = f & 1;
            if (t < 2) {
                f32x4 bv = *(const f32x4*)&qkv_b[t * 256 + h * 32 + dt * 16 + g * 4];
                int base = (t == 0) ? WB : WB + 2000;
#pragma unroll
                for (int tt = 0; tt < 4; ++tt) {
                    int row = tt * 16 + c;          // token
                    float v0 = acc[f][tt][0] + bv[0];
                    float v1 = acc[f][tt][1] + bv[1];
                    float v2 = acc[f][tt][2] + bv[2];
                    float v3 = acc[f][tt][3] + bv[3];
                    if (t == 0) {
                        v0 *= QK_SCALE_L2E; v1 *= QK_SCALE_L2E;
                        v2 *= QK_SCALE_L2E; v3 *= QK_SCALE_L2E;
                    }
                    if (row < 50) {
                        u32x2 s;
                        s[0] = pk2(v0, v1);
                        s[1] = pk2(v2, v3);
                        *(u32x2*)&sm[base + row * 40 + dt * 16 + g * 4] = s;
                    }
                }
            } else {
                float bvs = qkv_b[512 + h * 32 + dt * 16 + c];   // ch = lane col
#pragma unroll
                for (int tt = 0; tt < 4; ++tt) {
                    // rows = tokens tt*16+g*4+j, col ch = dt*16+c
                    u32x2 s;
                    s[0] = pk2(acc[f][tt][0] + bvs, acc[f][tt][1] + bvs);
                    s[1] = pk2(acc[f][tt][2] + bvs, acc[f][tt][3] + bvs);
                    *(u32x2*)&sm[WB + 4000 + (dt * 16 + c) * 72 + tt * 16 + g * 4] = s;
                }
            }
        }

        // ---- operand frags: Kf (A, lane=k-token), Qf (B, lane=q-token) from LDS ----
        s16x8 Qf[4], Kf[4];
#pragma unroll
        for (int nt = 0; nt < 4; ++nt) {
            int row = nt * 16 + c; row = row > 49 ? 49 : row;
            Qf[nt] = *(const s16x8*)&sm[WB + row * 40 + g * 8];
        }
#pragma unroll
        for (int mt = 0; mt < 4; ++mt) {
            int row = mt * 16 + c; row = row > 49 ? 49 : row;
            Kf[mt] = *(const s16x8*)&sm[WB + 2000 + row * 40 + g * 8];
        }

        // ---- streamed per q-column: {bm, St, softmax, P->LDS, PV, opk} ----
#pragma unroll
        for (int ntQ = 0; ntQ < 4; ++ntQ) {
            f32x4 bmfc[4];
            u32 bm0c[4], bm1c[4];
            if constexpr (F32BM) {
#pragma unroll
                for (int mtK = 0; mtK < 4; ++mtK)
                    bmfc[mtK] = *(const f32x4*)&bmF[((((wi * 8 + h) * 4 + ntQ) * 4 + mtK) * 64 + lane) * 4];
            } else {
#pragma unroll
                for (int mtK = 0; mtK < 4; ++mtK) {
                    const u32* bp = (const u32*)&bmC2[((((wi * 8 + h) * 4 + ntQ) * 4 + mtK) * 64 + lane) * 4];
                    bm0c[mtK] = bp[0];
                    bm1c[mtK] = bp[1];
                }
            }
            f32x4 lvc[4];
            __builtin_amdgcn_s_setprio(1);
#pragma unroll
            for (int mtK = 0; mtK < 4; ++mtK) {
                if constexpr (F32BM) {
                    lvc[mtK] = __builtin_amdgcn_mfma_f32_16x16x32_bf16(Kf[mtK], Qf[ntQ], bmfc[mtK], 0, 0, 0);
                } else {
                    f32x4 z = {0.f, 0.f, 0.f, 0.f};
                    lvc[mtK] = __builtin_amdgcn_mfma_f32_16x16x32_bf16(Kf[mtK], Qf[ntQ], z, 0, 0, 0);
                }
            }
            __builtin_amdgcn_s_setprio(0);
            float m = -1e30f;
#pragma unroll
            for (int mtK = 0; mtK < 3; ++mtK) {
                if constexpr (!F32BM) {
                    u32 w0 = bm0c[mtK], w1 = bm1c[mtK];
                    lvc[mtK][0] += __builtin_bit_cast(float, w0 << 16);
                    lvc[mtK][1] += __builtin_bit_cast(float, w0 & 0xffff0000u);
                    lvc[mtK][2] += __builtin_bit_cast(float, w1 << 16);
                    lvc[mtK][3] += __builtin_bit_cast(float, w1 & 0xffff0000u);
                }
                m = fmaxf(m, fmaxf(fmaxf(lvc[mtK][0], lvc[mtK][1]),
                                   fmaxf(lvc[mtK][2], lvc[mtK][3])));
            }
            if constexpr (!F32BM)
                lvc[3][0] += __builtin_bit_cast(float, bm0c[3] << 16);
            m = fmaxf(m, lvc[3][0]);     // bm=-1e30 zeroes dead lanes' e3 below
            m = fmaxf(m, swap16(m, l16));
            m = fmaxf(m, swap32(m, lo));
            float s = 0.f;
#pragma unroll
            for (int mtK = 0; mtK < 3; ++mtK)
#pragma unroll
                for (int j = 0; j < 4; ++j) {
                    float e = __builtin_amdgcn_exp2f(lvc[mtK][j] - m);
                    lvc[mtK][j] = e;
                    s += e;
                }
            float e3 = __builtin_amdgcn_exp2f(lvc[3][0] - m);
            s += e3;
            s += swap16(s, l16);
            s += swap32(s, lo);
            float is = __builtin_amdgcn_rcpf(s);

            // P -> LDS [q][k], normalized bf16, packed b64 (q<50)
            int q = ntQ * 16 + c;
            if (q < 50) {
#pragma unroll
                for (int mtK = 0; mtK < 3; ++mtK) {
                    u32x2 sP;
                    sP[0] = pk2(lvc[mtK][0] * is, lvc[mtK][1] * is);
                    sP[1] = pk2(lvc[mtK][2] * is, lvc[mtK][3] * is);
                    *(u32x2*)&sm[WB + q * 72 + mtK * 16 + g * 4] = sP;
                }
                u32x2 sP3;
                sP3[0] = pk2(e3 * is, 0.f);
                sP3[1] = 0;
                *(u32x2*)&sm[WB + q * 72 + 48 + g * 4] = sP3;
            }

            // PV: A = P-frag (lane=q-row) b128, B = VT b128; write opk
            int prow = q > 49 ? 49 : q;
            f32x4 o[2] = {{0.f, 0.f, 0.f, 0.f}, {0.f, 0.f, 0.f, 0.f}};
#pragma unroll
            for (int ks2 = 0; ks2 < 2; ++ks2) {
                s16x8 Pf = *(const s16x8*)&sm[WB + prow * 72 + ks2 * 32 + g * 8];
                s16x8 Vf0 = *(const s16x8*)&sm[WB + 4000 + c * 72 + ks2 * 32 + g * 8];
                s16x8 Vf1 = *(const s16x8*)&sm[WB + 4000 + (16 + c) * 72 + ks2 * 32 + g * 8];
                __builtin_amdgcn_s_setprio(1);
                o[0] = __builtin_amdgcn_mfma_f32_16x16x32_bf16(Pf, Vf0, o[0], 0, 0, 0);
                o[1] = __builtin_amdgcn_mfma_f32_16x16x32_bf16(Pf, Vf1, o[1], 0, 0, 0);
                __builtin_amdgcn_s_setprio(0);
            }
#pragma unroll
            for (int ndt = 0; ndt < 2; ++ndt) {
                opk[hl][ntQ][ndt][0] = pk2(o[ndt][0], o[ndt][1]);
                opk[hl][ntQ][ndt][1] = pk2(o[ndt][2], o[ndt][3]);
            }
        }
    }

    __syncthreads();   // all waves done with XS reads / wave scratch
    // stage head outputs into OUTS (overlaps XS, base 0)
#pragma unroll
    for (int hl = 0; hl < 2; ++hl)
#pragma unroll
        for (int mt = 0; mt < 4; ++mt)
#pragma unroll
            for (int n2 = 0; n2 < 2; ++n2)
#pragma unroll
                for (int jj = 0; jj < 2; ++jj) {
                    u32 w = opk[hl][mt][n2][jj];
                    int row = mt * 16 + g * 4 + jj * 2;
                    int colb = (wv * 2 + hl) * 32 + n2 * 16 + c;
                    if (row < 49)     sm[row * 264 + colb] = (u16)(w & 0xffffu);
                    if (row + 1 < 49) sm[(row + 1) * 264 + colb] = (u16)(w >> 16);
                }

    // prefetch proj ks=0 weight frags; they complete during the barrier drain
    s16x8 pf[2][4];
#pragma unroll
    for (int n = 0; n < 4; ++n)
        pf[0][n] = *(const s16x8*)&projwC[(((wv * 4 + n) * 8 + 0) * 64 + lane) * 8];
    __syncthreads();

    // ---- output projection: wave wv covers cols [wv*64, wv*64+64), dbuf weights ----
    f32x4 pacc[4][4];
#pragma unroll
    for (int mt = 0; mt < 4; ++mt)
#pragma unroll
        for (int n = 0; n < 4; ++n) pacc[mt][n] = f32x4{0.f, 0.f, 0.f, 0.f};
#pragma unroll
    for (int ks = 0; ks < 8; ++ks) {
        if (ks < 7) {
#pragma unroll
            for (int n = 0; n < 4; ++n)
                pf[(ks + 1) & 1][n] =
                    *(const s16x8*)&projwC[(((wv * 4 + n) * 8 + (ks + 1)) * 64 + lane) * 8];
        }
        s16x8 ao[4];
#pragma unroll
        for (int mt = 0; mt < 4; ++mt) {
            int row = mt * 16 + c; row = row > 48 ? 48 : row;
            ao[mt] = *(const s16x8*)&sm[row * 264 + ks * 32 + g * 8];
        }
        __builtin_amdgcn_s_setprio(1);
#pragma unroll
        for (int n = 0; n < 4; ++n)
#pragma unroll
            for (int mt = 0; mt < 4; ++mt)
                pacc[mt][n] = __builtin_amdgcn_mfma_f32_16x16x32_bf16(ao[mt], pf[ks & 1][n], pacc[mt][n], 0, 0, 0);
        __builtin_amdgcn_s_setprio(0);
    }
    float* ob = out + (size_t)b * 12544;
#pragma unroll
    for (int n = 0; n < 4; ++n) {
        int col = (wv * 4 + n) * 16 + c;
        float pb = proj_b[col];
#pragma unroll
        for (int mt = 0; mt < 4; ++mt)
#pragma unroll
            for (int j = 0; j < 4; ++j) {
                int row = mt * 16 + g * 4 + j;
                if (row < 49) ob[row * 256 + col] = pacc[mt][n][j] + pb;
            }
    }
}

extern "C" void kernel_launch(void* const* d_in, const int* in_sizes, int n_in,
                              void* d_out, int out_size, void* d_ws, size_t ws_size,
                              hipStream_t stream) {
    const float* x          = (const float*)d_in[0];
    const float* mask       = (const float*)d_in[1];
    const float* qkv_w      = (const float*)d_in[2];
    const float* qkv_b      = (const float*)d_in[3];
    const float* bias_table = (const float*)d_in[4];
    const float* proj_w     = (const float*)d_in[5];
    const float* proj_b     = (const float*)d_in[6];
    const int*   rel_index  = (const int*)d_in[7];

    u16*   wqkvC2 = (u16*)d_ws;
    u16*   projwC = (u16*)((char*)d_ws + WS_PROJW);
    u16*   bmC2   = (u16*)((char*)d_ws + WS_BMC);
    float* bmF    = (float*)((char*)d_ws + WS_BMC);

    const bool f32bm = ws_size >= (size_t)WS_F32_NEED;

    prep<<<8192, 256, 0, stream>>>(qkv_w, proj_w, bias_table, rel_index, mask,
                                   wqkvC2, projwC, bmC2, bmF, (int)f32bm);
    if (f32bm)
        swin_attn<true><<<2048, 256, 0, stream>>>(x, qkv_b, proj_b, wqkvC2, projwC,
                                                  bmC2, bmF, (float*)d_out);
    else
        swin_attn<false><<<2048, 256, 0, stream>>>(x, qkv_b, proj_b, wqkvC2, projwC,
                                                   bmC2, bmF, (float*)d_out);
}

// Round 22
// 105.692 us; speedup vs baseline: 1.0315x; 1.0315x over previous
//
#include <hip/hip_runtime.h>

typedef float f32x4 __attribute__((ext_vector_type(4)));
typedef short s16x8 __attribute__((ext_vector_type(8)));
typedef unsigned int u32x2 __attribute__((ext_vector_type(2)));
typedef __bf16 bf16x2 __attribute__((ext_vector_type(2)));
typedef unsigned short u16;
typedef unsigned int u32;

#define LOG2E    1.4426950408889634f
#define QK_SCALE_L2E 0.25504614517377436f  // 32^-0.5 * LOG2E

__device__ __forceinline__ u16 f2bf(float f) {
    __bf16 b = (__bf16)f;
    return __builtin_bit_cast(u16, b);
}
__device__ __forceinline__ u32 pk2(float lo, float hi) {
    bf16x2 v;
    v[0] = (__bf16)lo;
    v[1] = (__bf16)hi;
    return __builtin_bit_cast(u32, v);
}
__device__ __forceinline__ float swap32(float v, bool lt32) {
    u32 xi = __builtin_bit_cast(u32, v);
    u32x2 r = __builtin_amdgcn_permlane32_swap(xi, xi, false, false);
    return __builtin_bit_cast(float, lt32 ? r[1] : r[0]);
}
__device__ __forceinline__ float swap16(float v, bool lo16) {
    u32 xi = __builtin_bit_cast(u32, v);
    u32x2 r = __builtin_amdgcn_permlane16_swap(xi, xi, false, false);
    return __builtin_bit_cast(float, lo16 ? r[1] : r[0]);
}

// C-frag(pair) -> operand-frag conversion (dst lane (c,g) elem e <- src lane c+32*(g&1))
typedef unsigned int u32x4 __attribute__((ext_vector_type(4)));
__device__ __forceinline__ s16x8 frag4(u32 r0u0, u32 r1u0, u32 r0u1, u32 r1u1,
                                       int aA, int aB, bool lo) {
    u32x4 w;
    u32 a, bq;
    a  = (u32)__builtin_amdgcn_ds_bpermute(aA, (int)r0u0);
    bq = (u32)__builtin_amdgcn_ds_bpermute(aA, (int)r0u1);
    w[0] = lo ? a : bq;
    a  = (u32)__builtin_amdgcn_ds_bpermute(aA, (int)r1u0);
    bq = (u32)__builtin_amdgcn_ds_bpermute(aA, (int)r1u1);
    w[1] = lo ? a : bq;
    a  = (u32)__builtin_amdgcn_ds_bpermute(aB, (int)r0u0);
    bq = (u32)__builtin_amdgcn_ds_bpermute(aB, (int)r0u1);
    w[2] = lo ? a : bq;
    a  = (u32)__builtin_amdgcn_ds_bpermute(aB, (int)r1u0);
    bq = (u32)__builtin_amdgcn_ds_bpermute(aB, (int)r1u1);
    w[3] = lo ? a : bq;
    return __builtin_bit_cast(s16x8, w);
}

// ---- workspace byte offsets ----
#define WS_PROJW 393216
#define WS_BMC   524288
#define WS_F32_NEED (524288 + 8388608)

__global__ void prep(const float* __restrict__ qkv_w, const float* __restrict__ proj_w,
                     const float* __restrict__ bias_table, const int* __restrict__ rel_index,
                     const float* __restrict__ mask,
                     u16* __restrict__ wqkvC2, u16* __restrict__ projwC,
                     u16* __restrict__ bmC2, float* __restrict__ bmF, int use_f32) {
    int i = blockIdx.x * 256 + threadIdx.x;
    if (i < 196608) {                       // qkv weights: A-frags (Q,K) / B-frags (V)
        int e = i & 7, lane = (i >> 3) & 63, ks = (i >> 9) & 7, dt = (i >> 12) & 1;
        int i2 = i >> 13, t = i2 % 3, h = i2 / 3;
        int c = lane & 15, g = lane >> 4;
        wqkvC2[i] = f2bf(qkv_w[(t * 256 + h * 32 + dt * 16 + c) * 256 + ks * 32 + g * 8 + e]);
    }
    if (i < 65536) {                        // proj weights -> fragment order
        int e = i & 7, lane = (i >> 3) & 63, ks = (i >> 9) & 7, nt = (i >> 12) & 15;
        int c = lane & 15, g = lane >> 4;
        projwC[i] = f2bf(proj_w[(nt * 16 + c) * 256 + ks * 32 + g * 8 + e]);
    }
    {                                       // merged bias+mask (x LOG2E), St C-frag order
        int j = i & 3, lane = (i >> 2) & 63, mtK = (i >> 8) & 3, ntQ = (i >> 10) & 3;
        int h = (i >> 12) & 7, wi = i >> 15;
        int c = lane & 15, g = lane >> 4;
        int q = ntQ * 16 + c, k = mtK * 16 + g * 4 + j;
        float v;
        if (k < 49) v = (q < 49) ? bias_table[rel_index[q * 49 + k] * 8 + h]
                                   + mask[wi * 2401 + q * 49 + k]
                                 : 0.f;
        else        v = -1e30f;
        v *= LOG2E;
        if (use_f32) bmF[i] = v;
        else         bmC2[i] = f2bf(v);
    }
}

// ---- LDS (u16 offsets), total 35088 u16 = 70,176 B -> 2 blocks/CU ----
// XS  : [0, 12936)  49 rows x 264  (x window, bf16)
// VT  : 12936 + wv*2304, [ch32][tok72-pad] per wave
// OUTS: [22152, 35088)  49 rows x 264
#define OUTSB 22152
template<bool F32BM>
__global__ __launch_bounds__(256, 2)
void swin_attn(const float* __restrict__ x,
               const float* __restrict__ qkv_b,
               const float* __restrict__ proj_b,
               const u16* __restrict__ wqkvC2,
               const u16* __restrict__ projwC,
               const u16* __restrict__ bmC2,
               const float* __restrict__ bmF,
               float* __restrict__ out) {
    __shared__ __align__(16) u16 sm[35088];
    const int b = blockIdx.x, tid = threadIdx.x;
    const int wv = tid >> 6, lane = tid & 63, g = lane >> 4, c = lane & 15;
    const int wi = b & 63;
    const int VTb = 12936 + wv * 2304;
    const float* xw = x + (size_t)b * 12544;

    // stage x window (bf16), rows 0..48 — packed cvt + 8B stores
    for (int i = tid; i < 49 * 64; i += 256) {
        int row = i >> 6, q4 = i & 63;
        float4 v = ((const float4*)xw)[i];
        uint2 s;
        s.x = pk2(v.x, v.y);
        s.y = pk2(v.z, v.w);
        *(uint2*)&sm[row * 264 + q4 * 4] = s;
    }
    __syncthreads();

    const int addrA = ((lane & 15) + ((lane & 16) << 1)) << 2;
    const int addrB = addrA + 64;
    const bool lo = lane < 32;
    const bool l16 = (lane & 16) == 0;
    const s16x8 zfrag = {0, 0, 0, 0, 0, 0, 0, 0};

    // head-invariant Xf[ks=0] kept in registers; head-0 weight frags prefetched
    s16x8 XfInit[4];
#pragma unroll
    for (int tt = 0; tt < 4; ++tt)
        XfInit[tt] = *(const s16x8*)&sm[(tt * 16 + c) * 264 + g * 8];
    if (c > 0) XfInit[3] = zfrag;
    s16x8 wfN[6];
#pragma unroll
    for (int f = 0; f < 6; ++f)
        wfN[f] = *(const s16x8*)&wqkvC2[((((wv * 2) * 6 + f) * 8 + 0) * 64 + lane) * 8];

#pragma unroll
    for (int hl = 0; hl < 2; ++hl) {
        const int h = wv * 2 + hl;

        // ---- QKV: Q,K as W·X^T; V as X·Wv^T. dbuf weights + Xf ----
        f32x4 acc[6][4];
#pragma unroll
        for (int f = 0; f < 6; ++f)
#pragma unroll
            for (int tt = 0; tt < 4; ++tt) acc[f][tt] = f32x4{0.f, 0.f, 0.f, 0.f};

        s16x8 wf[2][6];
#pragma unroll
        for (int f = 0; f < 6; ++f) wf[0][f] = wfN[f];
        s16x8 Xf[2][4];
#pragma unroll
        for (int tt = 0; tt < 4; ++tt) Xf[0][tt] = XfInit[tt];
#pragma unroll
        for (int ks = 0; ks < 8; ++ks) {
            if (ks < 7) {
#pragma unroll
                for (int f = 0; f < 6; ++f)
                    wf[(ks + 1) & 1][f] =
                        *(const s16x8*)&wqkvC2[(((h * 6 + f) * 8 + (ks + 1)) * 64 + lane) * 8];
#pragma unroll
                for (int tt = 0; tt < 4; ++tt)
                    Xf[(ks + 1) & 1][tt] = *(const s16x8*)&sm[(tt * 16 + c) * 264 + (ks + 1) * 32 + g * 8];
                if (c > 0) Xf[(ks + 1) & 1][3] = zfrag;
            }
            __builtin_amdgcn_s_setprio(1);
#pragma unroll
            for (int f = 0; f < 6; ++f)
#pragma unroll
                for (int tt = 0; tt < 4; ++tt) {
                    if (f < 4)
                        acc[f][tt] = __builtin_amdgcn_mfma_f32_16x16x32_bf16(wf[ks & 1][f], Xf[ks & 1][tt], acc[f][tt], 0, 0, 0);
                    else
                        acc[f][tt] = __builtin_amdgcn_mfma_f32_16x16x32_bf16(Xf[ks & 1][tt], wf[ks & 1][f], acc[f][tt], 0, 0, 0);
                }
            __builtin_amdgcn_s_setprio(0);
        }
        // prefetch next head's first weight frags (hide L2 under distribute+attention)
        if (hl == 0) {
#pragma unroll
            for (int f = 0; f < 6; ++f)
                wfN[f] = *(const s16x8*)&wqkvC2[((((h + 1) * 6 + f) * 8 + 0) * 64 + lane) * 8];
        }

        // ---- distribute: Q/K -> packed regs; V -> VT[ch][tok] packed b64 ----
        u32 qp[4][2][2], kp[4][2][2];
#pragma unroll
        for (int f = 0; f < 6; ++f) {
            int t = f >> 1, dt = f & 1;
            if (t < 2) {
                f32x4 bv = *(const f32x4*)&qkv_b[t * 256 + h * 32 + dt * 16 + g * 4];
#pragma unroll
                for (int tt = 0; tt < 4; ++tt) {
                    float v0 = acc[f][tt][0] + bv[0];
                    float v1 = acc[f][tt][1] + bv[1];
                    float v2 = acc[f][tt][2] + bv[2];
                    float v3 = acc[f][tt][3] + bv[3];
                    if (t == 0) {
                        qp[tt][dt][0] = pk2(v0 * QK_SCALE_L2E, v1 * QK_SCALE_L2E);
                        qp[tt][dt][1] = pk2(v2 * QK_SCALE_L2E, v3 * QK_SCALE_L2E);
                    } else {
                        kp[tt][dt][0] = pk2(v0, v1);
                        kp[tt][dt][1] = pk2(v2, v3);
                    }
                }
            } else {
                float bvs = qkv_b[512 + h * 32 + dt * 16 + c];   // V: C-frag col = ch
#pragma unroll
                for (int tt = 0; tt < 4; ++tt) {
                    u32x2 s;
                    s[0] = pk2(acc[f][tt][0] + bvs, acc[f][tt][1] + bvs);
                    s[1] = pk2(acc[f][tt][2] + bvs, acc[f][tt][3] + bvs);
                    *(u32x2*)&sm[VTb + (dt * 16 + c) * 72 + tt * 16 + g * 4] = s;
                }
            }
        }

        // ---- issue bias/mask loads early ----
        f32x4 bmf[4][4];
        u32 bm0[4][4], bm1[4][4];
        if constexpr (F32BM) {
#pragma unroll
            for (int ntQ = 0; ntQ < 4; ++ntQ)
#pragma unroll
                for (int mtK = 0; mtK < 4; ++mtK)
                    bmf[ntQ][mtK] = *(const f32x4*)&bmF[((((wi * 8 + h) * 4 + ntQ) * 4 + mtK) * 64 + lane) * 4];
        } else {
#pragma unroll
            for (int ntQ = 0; ntQ < 4; ++ntQ)
#pragma unroll
                for (int mtK = 0; mtK < 4; ++mtK) {
                    const u32* bp = (const u32*)&bmC2[((((wi * 8 + h) * 4 + ntQ) * 4 + mtK) * 64 + lane) * 4];
                    bm0[ntQ][mtK] = bp[0];
                    bm1[ntQ][mtK] = bp[1];
                }
        }

        // ---- operand frags for St = K·Q^T ----
        s16x8 Qf[4], Kf[4];
#pragma unroll
        for (int nt = 0; nt < 4; ++nt)
            Qf[nt] = frag4(qp[nt][0][0], qp[nt][0][1], qp[nt][1][0], qp[nt][1][1], addrA, addrB, lo);
#pragma unroll
        for (int mt = 0; mt < 4; ++mt)
            Kf[mt] = frag4(kp[mt][0][0], kp[mt][0][1], kp[mt][1][0], kp[mt][1][1], addrA, addrB, lo);

        // ---- St (bias as C-in when F32BM), lane-local softmax ----
        f32x4 lv[4][4];
        __builtin_amdgcn_s_setprio(1);
#pragma unroll
        for (int mtK = 0; mtK < 4; ++mtK)
#pragma unroll
            for (int ntQ = 0; ntQ < 4; ++ntQ) {
                if constexpr (F32BM) {
                    lv[mtK][ntQ] = __builtin_amdgcn_mfma_f32_16x16x32_bf16(Kf[mtK], Qf[ntQ], bmf[ntQ][mtK], 0, 0, 0);
                } else {
                    f32x4 z = {0.f, 0.f, 0.f, 0.f};
                    lv[mtK][ntQ] = __builtin_amdgcn_mfma_f32_16x16x32_bf16(Kf[mtK], Qf[ntQ], z, 0, 0, 0);
                }
            }
        __builtin_amdgcn_s_setprio(0);
        float mx[4];
#pragma unroll
        for (int ntQ = 0; ntQ < 4; ++ntQ) {
            float m = -1e30f;
#pragma unroll
            for (int mtK = 0; mtK < 3; ++mtK) {
                if constexpr (!F32BM) {
                    u32 w0 = bm0[ntQ][mtK], w1 = bm1[ntQ][mtK];
                    lv[mtK][ntQ][0] += __builtin_bit_cast(float, w0 << 16);
                    lv[mtK][ntQ][1] += __builtin_bit_cast(float, w0 & 0xffff0000u);
                    lv[mtK][ntQ][2] += __builtin_bit_cast(float, w1 << 16);
                    lv[mtK][ntQ][3] += __builtin_bit_cast(float, w1 & 0xffff0000u);
                }
                m = fmaxf(m, fmaxf(fmaxf(lv[mtK][ntQ][0], lv[mtK][ntQ][1]),
                                   fmaxf(lv[mtK][ntQ][2], lv[mtK][ntQ][3])));
            }
            if constexpr (!F32BM)
                lv[3][ntQ][0] += __builtin_bit_cast(float, bm0[ntQ][3] << 16);
            m = fmaxf(m, lv[3][ntQ][0]);
            mx[ntQ] = m;
        }
#pragma unroll
        for (int ntQ = 0; ntQ < 4; ++ntQ) {
            float m = mx[ntQ];
            m = fmaxf(m, swap16(m, l16));
            m = fmaxf(m, swap32(m, lo));
            mx[ntQ] = m;
        }
        float sums[4] = {0.f, 0.f, 0.f, 0.f};
#pragma unroll
        for (int ntQ = 0; ntQ < 4; ++ntQ) {
#pragma unroll
            for (int mtK = 0; mtK < 3; ++mtK)
#pragma unroll
                for (int j = 0; j < 4; ++j) {
                    float e = __builtin_amdgcn_exp2f(lv[mtK][ntQ][j] - mx[ntQ]);
                    lv[mtK][ntQ][j] = e;
                    sums[ntQ] += e;
                }
            float e3 = __builtin_amdgcn_exp2f(lv[3][ntQ][0] - mx[ntQ]);
            lv[3][ntQ][0] = e3;
            sums[ntQ] += e3;
        }
#pragma unroll
        for (int ntQ = 0; ntQ < 4; ++ntQ) {
            float s = sums[ntQ];
            s += swap16(s, l16);
            s += swap32(s, lo);
            sums[ntQ] = __builtin_amdgcn_rcpf(s);
        }
        // normalized P packed
        u32 pp[4][4][2];
#pragma unroll
        for (int ntQ = 0; ntQ < 4; ++ntQ) {
            float is = sums[ntQ];
#pragma unroll
            for (int mtK = 0; mtK < 3; ++mtK) {
                pp[mtK][ntQ][0] = pk2(lv[mtK][ntQ][0] * is, lv[mtK][ntQ][1] * is);
                pp[mtK][ntQ][1] = pk2(lv[mtK][ntQ][2] * is, lv[mtK][ntQ][3] * is);
            }
            pp[3][ntQ][0] = pk2(lv[3][ntQ][0] * is, 0.f);
            pp[3][ntQ][1] = 0;
        }

        // ---- PV: A = P-frag (bpermute), B = VT from LDS; write OUTS directly ----
#pragma unroll
        for (int mtQ = 0; mtQ < 4; ++mtQ) {
            f32x4 o[2] = {{0.f, 0.f, 0.f, 0.f}, {0.f, 0.f, 0.f, 0.f}};
#pragma unroll
            for (int ks2 = 0; ks2 < 2; ++ks2) {
                s16x8 Pf = frag4(pp[2 * ks2][mtQ][0], pp[2 * ks2][mtQ][1],
                                 pp[2 * ks2 + 1][mtQ][0], pp[2 * ks2 + 1][mtQ][1], addrA, addrB, lo);
                s16x8 Vf0 = *(const s16x8*)&sm[VTb + (0 * 16 + c) * 72 + ks2 * 32 + g * 8];
                s16x8 Vf1 = *(const s16x8*)&sm[VTb + (1 * 16 + c) * 72 + ks2 * 32 + g * 8];
                __builtin_amdgcn_s_setprio(1);
                o[0] = __builtin_amdgcn_mfma_f32_16x16x32_bf16(Pf, Vf0, o[0], 0, 0, 0);
                o[1] = __builtin_amdgcn_mfma_f32_16x16x32_bf16(Pf, Vf1, o[1], 0, 0, 0);
                __builtin_amdgcn_s_setprio(0);
            }
#pragma unroll
            for (int ndt = 0; ndt < 2; ++ndt) {
                int colb = (wv * 2 + hl) * 32 + ndt * 16 + c;
                int row = mtQ * 16 + g * 4;
                if (row < 49)     sm[OUTSB + row * 264 + colb] = f2bf(o[ndt][0]);
                if (row + 1 < 49) sm[OUTSB + (row + 1) * 264 + colb] = f2bf(o[ndt][1]);
                if (row + 2 < 49) sm[OUTSB + (row + 2) * 264 + colb] = f2bf(o[ndt][2]);
                if (row + 3 < 49) sm[OUTSB + (row + 3) * 264 + colb] = f2bf(o[ndt][3]);
            }
        }
    }

    // prefetch proj ks=0 weight frags; they complete during the barrier drain
    s16x8 pf[2][4];
#pragma unroll
    for (int n = 0; n < 4; ++n)
        pf[0][n] = *(const s16x8*)&projwC[(((wv * 4 + n) * 8 + 0) * 64 + lane) * 8];
    __syncthreads();   // single barrier: all OUTS/VT writes visible

    // ---- output projection: wave wv covers cols [wv*64, wv*64+64), dbuf weights ----
    f32x4 pacc[4][4];
#pragma unroll
    for (int mt = 0; mt < 4; ++mt)
#pragma unroll
        for (int n = 0; n < 4; ++n) pacc[mt][n] = f32x4{0.f, 0.f, 0.f, 0.f};
#pragma unroll
    for (int ks = 0; ks < 8; ++ks) {
        if (ks < 7) {
#pragma unroll
            for (int n = 0; n < 4; ++n)
                pf[(ks + 1) & 1][n] =
                    *(const s16x8*)&projwC[(((wv * 4 + n) * 8 + (ks + 1)) * 64 + lane) * 8];
        }
        s16x8 ao[4];
#pragma unroll
        for (int mt = 0; mt < 4; ++mt) {
            int row = mt * 16 + c; row = row > 48 ? 48 : row;
            ao[mt] = *(const s16x8*)&sm[OUTSB + row * 264 + ks * 32 + g * 8];
        }
        __builtin_amdgcn_s_setprio(1);
#pragma unroll
        for (int n = 0; n < 4; ++n)
#pragma unroll
            for (int mt = 0; mt < 4; ++mt)
                pacc[mt][n] = __builtin_amdgcn_mfma_f32_16x16x32_bf16(ao[mt], pf[ks & 1][n], pacc[mt][n], 0, 0, 0);
        __builtin_amdgcn_s_setprio(0);
    }
    float* ob = out + (size_t)b * 12544;
#pragma unroll
    for (int n = 0; n < 4; ++n) {
        int col = (wv * 4 + n) * 16 + c;
        float pb = proj_b[col];
#pragma unroll
        for (int mt = 0; mt < 4; ++mt)
#pragma unroll
            for (int j = 0; j < 4; ++j) {
                int row = mt * 16 + g * 4 + j;
                if (row < 49) ob[row * 256 + col] = pacc[mt][n][j] + pb;
            }
    }
}

extern "C" void kernel_launch(void* const* d_in, const int* in_sizes, int n_in,
                              void* d_out, int out_size, void* d_ws, size_t ws_size,
                              hipStream_t stream) {
    const float* x          = (const float*)d_in[0];
    const float* mask       = (const float*)d_in[1];
    const float* qkv_w      = (const float*)d_in[2];
    const float* qkv_b      = (const float*)d_in[3];
    const float* bias_table = (const float*)d_in[4];
    const float* proj_w     = (const float*)d_in[5];
    const float* proj_b     = (const float*)d_in[6];
    const int*   rel_index  = (const int*)d_in[7];

    u16*   wqkvC2 = (u16*)d_ws;
    u16*   projwC = (u16*)((char*)d_ws + WS_PROJW);
    u16*   bmC2   = (u16*)((char*)d_ws + WS_BMC);
    float* bmF    = (float*)((char*)d_ws + WS_BMC);

    const bool f32bm = ws_size >= (size_t)WS_F32_NEED;

    prep<<<8192, 256, 0, stream>>>(qkv_w, proj_w, bias_table, rel_index, mask,
                                   wqkvC2, projwC, bmC2, bmF, (int)f32bm);
    if (f32bm)
        swin_attn<true><<<2048, 256, 0, stream>>>(x, qkv_b, proj_b, wqkvC2, projwC,
                                                  bmC2, bmF, (float*)d_out);
    else
        swin_attn<false><<<2048, 256, 0, stream>>>(x, qkv_b, proj_b, wqkvC2, projwC,
                                                   bmC2, bmF, (float*)d_out);
}